// Round 9
// baseline (71.661 us; speedup 1.0000x reference)
//
#include <hip/hip_runtime.h>

// KalmanStaticFilter: per-row linear recurrence s_{t+1} = M s_t + c z_t
//   M = [[1-a-b, 1], [-b, 1]], c = [a+b, b], output x_t = (1-a) p_t + a z_t
// R9: unroll-4 coefficient form. s_{t+4} = M^4 s_t + sum_i M^(3-i) c z_{t+i};
// x_{t..t+3} are independent affine fns of (s_t, z...) -> serial chain per 4
// elems drops from ~12 dependent ops to ~3. All LDS ops are aligned b128
// (STRIDE=36 floats, bank-uniform). Barrier-free single-wave blocks (R8).

#define A_CONST 0.85f
#define B_CONST 0.005f

typedef float vfloat4 __attribute__((ext_vector_type(4)));

constexpr int ROWS   = 4096;
constexpr int T      = 8192;
constexpr int W      = 2048;     // section width (one wave)
constexpr int L      = 32;       // per-lane chunk length
constexpr int NSEC   = T / W;    // 4
constexpr int STRIDE = 36;       // floats; 144 B, 16B-aligned, bank-uniform

__global__ __launch_bounds__(64)
void kalman_kernel(const float* __restrict__ Z, float* __restrict__ X) {
    const int lane = threadIdx.x;        // one wave per block
    const int row  = blockIdx.x;

    __shared__ float buf[64 * STRIDE];   // 9216 B

    const float* Zr = Z + (size_t)row * T;
    float*       Xr = X + (size_t)row * T;

    // ---------------- f64 coefficient precompute (once) ----------------
    const double da = (double)A_CONST, db = (double)B_CONST;
    double M1[4] = { 1.0 - da - db, 1.0, -db, 1.0 };     // 00,01,10,11
    auto mm = [](const double* A, const double* B, double* D) {
        D[0] = A[0]*B[0] + A[1]*B[2]; D[1] = A[0]*B[1] + A[1]*B[3];
        D[2] = A[2]*B[0] + A[3]*B[2]; D[3] = A[2]*B[1] + A[3]*B[3];
    };
    double M2[4], M3[4], M4[4];
    mm(M1, M1, M2); mm(M2, M1, M3); mm(M2, M2, M4);
    double c0 = da + db, c1 = db;                        // c
    double q0[2] = { c0, c1 };
    double q1[2] = { M1[0]*c0 + M1[1]*c1, M1[2]*c0 + M1[3]*c1 };
    double q2[2] = { M2[0]*c0 + M2[1]*c1, M2[2]*c0 + M2[3]*c1 };
    double q3[2] = { M3[0]*c0 + M3[1]*c1, M3[2]*c0 + M3[3]*c1 };

    // s-update constants (fp32)
    const float m400 = (float)M4[0], m401 = (float)M4[1];
    const float m410 = (float)M4[2], m411 = (float)M4[3];
    const float cp0 = (float)q3[0], cp1 = (float)q2[0], cp2 = (float)q1[0], cp3 = (float)q0[0];
    const float cv0 = (float)q3[1], cv1 = (float)q2[1], cv2 = (float)q1[1], cv3 = (float)q0[1];

    // output constants (fp32): x_j = oa*z_j + ob_j*p + oc_j*v + sum_i od_{j,i}*z_i
    const double one_a = 1.0 - da;
    const float oa  = (float)da;
    const float ob0 = (float)one_a;
    const float ob1 = (float)(one_a * M1[0]), oc1 = (float)(one_a * M1[1]);
    const float ob2 = (float)(one_a * M2[0]), oc2 = (float)(one_a * M2[1]);
    const float ob3 = (float)(one_a * M3[0]), oc3 = (float)(one_a * M3[1]);
    const float od10 = (float)(one_a * q0[0]);
    const float od20 = (float)(one_a * q1[0]), od21 = (float)(one_a * q0[0]);
    const float od30 = (float)(one_a * q2[0]), od31 = (float)(one_a * q1[0]), od32 = (float)(one_a * q0[0]);

    // scan-stage constants G[k] = M^(32*2^k), k=0..6
    double g[7][4];
    mm(M4, M4, g[0]); mm(g[0], g[0], g[0]); mm(g[0], g[0], g[0]);   // M^32
    #pragma unroll
    for (int k = 1; k < 7; ++k) mm(g[k-1], g[k-1], g[k]);
    float sc00[6], sc01[6], sc10[6], sc11[6];
    #pragma unroll
    for (int k = 0; k < 6; ++k) {
        sc00[k] = (float)g[k][0]; sc01[k] = (float)g[k][1];
        sc10[k] = (float)g[k][2]; sc11[k] = (float)g[k][3];
    }
    const float w00 = (float)g[6][0], w01 = (float)g[6][1];   // M^2048
    const float w10 = (float)g[6][2], w11 = (float)g[6][3];

    // per-lane matrix A32^lane via bit product
    double lm[4] = { 1.0, 0.0, 0.0, 1.0 };
    #pragma unroll
    for (int k = 0; k < 6; ++k) {
        if ((lane >> k) & 1) { double t[4]; mm(g[k], lm, t); lm[0]=t[0]; lm[1]=t[1]; lm[2]=t[2]; lm[3]=t[3]; }
    }
    const float La00 = (float)lm[0], La01 = (float)lm[1];
    const float La10 = (float)lm[2], La11 = (float)lm[3];

    // ---------------- main loop ----------------
    float ps = Zr[0];
    float vs = 0.0f;

    float4 r[8];
    {
        const float4* src = (const float4*)Zr;
        #pragma unroll
        for (int i = 0; i < 8; ++i) r[i] = src[i * 64 + lane];
    }

    for (int s = 0; s < NSEC; ++s) {
        // ---- stage regs into LDS (chunk-transpose, aligned b128) ----
        #pragma unroll
        for (int i = 0; i < 8; ++i) {
            int f = i * 64 + lane;
            int c = f >> 3;
            int j = (f & 7) << 2;
            *(float4*)(buf + c * STRIDE + j) = r[i];
        }

        // ---- issue next section's loads (fly under all compute below) ----
        if (s + 1 < NSEC) {
            const float4* src = (const float4*)(Zr + (s + 1) * W);
            #pragma unroll
            for (int i = 0; i < 8; ++i) r[i] = src[i * 64 + lane];
        }

        // ---- pass A: chunk offset from s=(0,0), unroll-4; z kept in regs ----
        float4 z4[8];
        float bp, bv;
        {
            float p = 0.0f, v = 0.0f;
            const float4* zc = (const float4*)(buf + lane * STRIDE);
            #pragma unroll
            for (int gi = 0; gi < 8; ++gi) {
                float4 z = zc[gi];
                z4[gi] = z;
                float zp = cp0*z.x + cp1*z.y + cp2*z.z + cp3*z.w;   // indep of s
                float zv = cv0*z.x + cv1*z.y + cv2*z.z + cv3*z.w;
                float np = m400*p + m401*v + zp;
                float nv = m410*p + m411*v + zv;
                p = np; v = nv;
            }
            bp = p; bv = v;
        }

        // ---- constant-matrix Kogge-Stone scan of offsets ----
        float sb0 = bp, sb1 = bv;
        #pragma unroll
        for (int k = 0; k < 6; ++k) {
            const int d = 1 << k;
            float ob0_ = __shfl_up(sb0, d);
            float ob1_ = __shfl_up(sb1, d);
            if (lane >= d) {
                sb0 = sc00[k]*ob0_ + sc01[k]*ob1_ + sb0;
                sb1 = sc10[k]*ob0_ + sc11[k]*ob1_ + sb1;
            }
        }
        float eb0 = __shfl_up(sb0, 1);
        float eb1 = __shfl_up(sb1, 1);
        if (lane == 0) { eb0 = 0.0f; eb1 = 0.0f; }
        float i0 = __shfl(sb0, 63);
        float i1 = __shfl(sb1, 63);

        float p   = La00*ps + La01*vs + eb0;
        float v   = La10*ps + La11*vs + eb1;
        float nps = w00*ps + w01*vs + i0;
        float nvs = w10*ps + w11*vs + i1;

        // ---- pass B: outputs via coefficient form (x0..x3 independent) ----
        {
            float4* zc = (float4*)(buf + lane * STRIDE);
            #pragma unroll
            for (int gi = 0; gi < 8; ++gi) {
                float4 z = z4[gi];
                float x0 = ob0*p + oa*z.x;
                float x1 = ob1*p + oc1*v + od10*z.x + oa*z.y;
                float x2 = ob2*p + oc2*v + od20*z.x + od21*z.y + oa*z.z;
                float x3 = ob3*p + oc3*v + od30*z.x + od31*z.y + od32*z.z + oa*z.w;
                float zp = cp0*z.x + cp1*z.y + cp2*z.z + cp3*z.w;
                float zv = cv0*z.x + cv1*z.y + cv2*z.z + cv3*z.w;
                float np = m400*p + m401*v + zp;
                float nv = m410*p + m411*v + zv;
                p = np; v = nv;
                zc[gi] = make_float4(x0, x1, x2, x3);
            }
        }

        // ---- unload: aligned b128 reads, coalesced nt stores ----
        {
            vfloat4* dst = (vfloat4*)(Xr + s * W);
            #pragma unroll
            for (int i = 0; i < 8; ++i) {
                int f = i * 64 + lane;
                int c = f >> 3;
                int j = (f & 7) << 2;
                float4 q = *(const float4*)(buf + c * STRIDE + j);
                vfloat4 v4 = { q.x, q.y, q.z, q.w };
                __builtin_nontemporal_store(v4, dst + f);
            }
        }

        ps = nps; vs = nvs;
        // barrier-free: single wave per block; LDS WAR ordered by lgkmcnt.
    }
}

extern "C" void kernel_launch(void* const* d_in, const int* in_sizes, int n_in,
                              void* d_out, int out_size, void* d_ws, size_t ws_size,
                              hipStream_t stream) {
    const float* Z = (const float*)d_in[0];
    float*       X = (float*)d_out;
    dim3 grid(ROWS), block(64);
    hipLaunchKernelGGL(kalman_kernel, grid, block, 0, stream, Z, X);
}